// Round 2
// baseline (687.349 us; speedup 1.0000x reference)
//
#include <hip/hip_runtime.h>
#include <hip/hip_bf16.h>

#define VOCAB 50257
#define NB    2048
#define NE    128
#define NCH   393              // ceil(VOCAB/128)
#define NWG   (NCH * (NB/128)) // 6288 = 8 * 786

typedef __bf16 bf16x8 __attribute__((ext_vector_type(8)));
typedef float  f32x4  __attribute__((ext_vector_type(4)));

// ---------------- kernel 1: recover indices from one-hot ----------------
__global__ void k_find_idx(const float4* __restrict__ oh, int* __restrict__ idx, long n4) {
  long stride = (long)gridDim.x * blockDim.x;
  for (long i = (long)blockIdx.x * blockDim.x + threadIdx.x; i < n4; i += stride) {
    float4 v = oh[i];
    if (v.x != 0.f || v.y != 0.f || v.z != 0.f || v.w != 0.f) {
      long j = i << 2;
      if (v.x != 0.f) { long p = j;     int b = (int)(p / VOCAB); idx[b] = (int)(p - (long)b * VOCAB); }
      if (v.y != 0.f) { long p = j + 1; int b = (int)(p / VOCAB); idx[b] = (int)(p - (long)b * VOCAB); }
      if (v.z != 0.f) { long p = j + 2; int b = (int)(p / VOCAB); idx[b] = (int)(p - (long)b * VOCAB); }
      if (v.w != 0.f) { long p = j + 3; int b = (int)(p / VOCAB); idx[b] = (int)(p - (long)b * VOCAB); }
    }
  }
}

// ---------------- kernel 2: w2 [128][V] f32 -> w2T [V][128] bf16 ----------------
__global__ void k_transpose(const float* __restrict__ w2, __hip_bfloat16* __restrict__ w2T) {
  __shared__ __hip_bfloat16 tile[64][130];
  const int v0 = blockIdx.x * 64;
  const int tv = threadIdx.x & 63;
  const int te = threadIdx.x >> 6;   // 0..3
  const int v  = v0 + tv;
#pragma unroll
  for (int e0 = 0; e0 < NE; e0 += 4) {
    int e = e0 + te;
    float val = (v < VOCAB) ? w2[(long)e * VOCAB + v] : 0.f;
    tile[tv][e] = __float2bfloat16(val);
  }
  __syncthreads();
#pragma unroll
  for (int it = 0; it < 16; ++it) {
    int f  = it * 256 + threadIdx.x;
    int r  = f >> 6;       // 0..63
    int c2 = f & 63;       // ushort2 index
    int vv = v0 + r;
    if (vv < VOCAB) {
      ushort2 p;
      p.x = *reinterpret_cast<const unsigned short*>(&tile[r][2 * c2]);
      p.y = *reinterpret_cast<const unsigned short*>(&tile[r][2 * c2 + 1]);
      reinterpret_cast<ushort2*>(w2T + (long)vv * NE)[c2] = p;
    }
  }
}

// ---------------- kernel 3: z1[b] = bf16(w1[idx[b]]) ----------------
__global__ void k_gather(const float* __restrict__ w1, const int* __restrict__ idx,
                         __hip_bfloat16* __restrict__ z1) {
  int t = blockIdx.x * blockDim.x + threadIdx.x;   // NB*NE threads
  int b = t >> 7, e = t & 127;
  z1[t] = __float2bfloat16(w1[(long)idx[b] * NE + e]);
}

// ---------------- GEMM (operand-swapped): acc[vi][ri] = w2T-frag x z1-frag ----------------
// D layout: z-row = l15 (per ri frag), vocab col = lhi*4 + reg (per vi frag) ->
// each lane holds 4 CONSECUTIVE vocab cols of one row per acc reg: float4 stores + cheap row-reduce.
template <bool LSE_PASS>
__global__ __launch_bounds__(256) void k_gemm(
    const __hip_bfloat16* __restrict__ z1,
    const __hip_bfloat16* __restrict__ w2T,
    const float* __restrict__ lse,
    float* __restrict__ pmax, float* __restrict__ psum,
    float* __restrict__ out) {
  __shared__ float sm[2][128];
  __shared__ float ss[2][128];
  // XCD-chunked swizzle: bid%8 = XCD (round-robin dispatch); give each XCD a
  // contiguous chunk-major slice so its w2T working set is ~1.6MB (L2-resident).
  const int bid = blockIdx.x;
  const int g = (bid & 7) * (NWG / 8) + (bid >> 3);
  const int chunk = g >> 4;          // 0..392 : vocab 128-col chunk
  const int rowg  = g & 15;          // 0..15  : batch 128-row group
  const int lane = threadIdx.x & 63;
  const int wave = threadIdx.x >> 6;
  const int wm = wave >> 1, wn = wave & 1;
  const int l15 = lane & 15, lhi = lane >> 4;
  const int row0 = rowg * 128 + wm * 64;
  const int col0 = chunk * 128 + wn * 64;

  // B operand: z1 rows (col index of D = z row)
  bf16x8 bz[4][4];
  {
    const __hip_bfloat16* zp = z1 + (row0 + l15) * NE + lhi * 8;
#pragma unroll
    for (int ri = 0; ri < 4; ++ri)
#pragma unroll
      for (int kb = 0; kb < 4; ++kb)
        bz[ri][kb] = *reinterpret_cast<const bf16x8*>(zp + ri * 16 * NE + kb * 32);
  }

  f32x4 acc[4][4];   // [vi][ri]
#pragma unroll
  for (int vi = 0; vi < 4; ++vi)
#pragma unroll
    for (int ri = 0; ri < 4; ++ri)
      acc[vi][ri] = (f32x4){0.f, 0.f, 0.f, 0.f};

#pragma unroll
  for (int vi = 0; vi < 4; ++vi) {
    int col  = col0 + vi * 16 + l15;
    int colc = col < VOCAB ? col : VOCAB - 1;   // clamped dup, masked in epilogue
    const __hip_bfloat16* wp = w2T + colc * NE + lhi * 8;
    bf16x8 aw[4];
#pragma unroll
    for (int kb = 0; kb < 4; ++kb)
      aw[kb] = *reinterpret_cast<const bf16x8*>(wp + kb * 32);
#pragma unroll
    for (int ri = 0; ri < 4; ++ri)
#pragma unroll
      for (int kb = 0; kb < 4; ++kb)
        acc[vi][ri] = __builtin_amdgcn_mfma_f32_16x16x32_bf16(aw[kb], bz[ri][kb], acc[vi][ri], 0, 0, 0);
  }

  if constexpr (LSE_PASS) {
#pragma unroll
    for (int ri = 0; ri < 4; ++ri) {
      // lane l15 owns row row0+ri*16+l15; its 16 values are cols col0+vi*16+lhi*4+r
      float v[16];
      float m = -INFINITY;
#pragma unroll
      for (int vi = 0; vi < 4; ++vi)
#pragma unroll
        for (int r = 0; r < 4; ++r) {
          int col = col0 + vi * 16 + lhi * 4 + r;
          float x = (col < VOCAB) ? acc[vi][ri][r] : -INFINITY;
          v[vi * 4 + r] = x;
          m = fmaxf(m, x);
        }
      m = fmaxf(m, __shfl_xor(m, 16));
      m = fmaxf(m, __shfl_xor(m, 32));     // row max over the wave's 64 cols
      float s = 0.f;
#pragma unroll
      for (int t = 0; t < 16; ++t) s += __expf(v[t] - m);   // exp(-inf)=0 masks OOB
      s += __shfl_xor(s, 16);
      s += __shfl_xor(s, 32);
      if (lhi == 0) {
        int lr = wm * 64 + ri * 16 + l15;
        sm[wn][lr] = m;
        ss[wn][lr] = s;
      }
    }
    __syncthreads();
    if (threadIdx.x < 128) {
      int r = threadIdx.x;
      float m0 = sm[0][r], m1 = sm[1][r];
      float s0 = ss[0][r], s1 = ss[1][r];
      float M = fmaxf(m0, m1);
      float S = s0 * __expf(m0 - M) + s1 * __expf(m1 - M);
      int o = chunk * NB + rowg * 128 + r;
      pmax[o] = M;
      psum[o] = S;
    }
  } else {
#pragma unroll
    for (int ri = 0; ri < 4; ++ri) {
      int row = row0 + ri * 16 + l15;
      float l = lse[row];
      float* op = out + row * VOCAB + col0 + lhi * 4;   // 4B-aligned only; HW ok for dwordx4
#pragma unroll
      for (int vi = 0; vi < 4; ++vi) {
        int col = col0 + vi * 16 + lhi * 4;
        if (col + 3 < VOCAB) {
          f32x4 w = acc[vi][ri] - l;
          __builtin_nontemporal_store(w, reinterpret_cast<f32x4*>(op + vi * 16));
        } else {
#pragma unroll
          for (int r = 0; r < 4; ++r)
            if (col + r < VOCAB) op[vi * 16 + r] = acc[vi][ri][r] - l;
        }
      }
    }
  }
}

// ---------------- two-stage chunk-partial merge -> lse[b] ----------------
__global__ void k_lse_part(const float* __restrict__ pmax, const float* __restrict__ psum,
                           float* __restrict__ m2, float* __restrict__ s2) {
  int b  = blockIdx.x * 256 + threadIdx.x;
  int cg = blockIdx.y;
  int c0 = cg * 50, c1 = (c0 + 50 < NCH) ? c0 + 50 : NCH;
  float M = -INFINITY;
  for (int c = c0; c < c1; ++c) M = fmaxf(M, pmax[c * NB + b]);
  float S = 0.f;
  for (int c = c0; c < c1; ++c) S += psum[c * NB + b] * __expf(pmax[c * NB + b] - M);
  m2[cg * NB + b] = M;
  s2[cg * NB + b] = S;
}

__global__ void k_lse_final(const float* __restrict__ m2, const float* __restrict__ s2,
                            float* __restrict__ lse) {
  int b = blockIdx.x * 256 + threadIdx.x;
  float M = -INFINITY;
#pragma unroll
  for (int g = 0; g < 8; ++g) M = fmaxf(M, m2[g * NB + b]);
  float S = 0.f;
#pragma unroll
  for (int g = 0; g < 8; ++g) S += s2[g * NB + b] * __expf(m2[g * NB + b] - M);
  lse[b] = M + __logf(S);
}

extern "C" void kernel_launch(void* const* d_in, const int* in_sizes, int n_in,
                              void* d_out, int out_size, void* d_ws, size_t ws_size,
                              hipStream_t stream) {
  const float* one_hot = (const float*)d_in[0];
  const float* w1      = (const float*)d_in[1];
  const float* w2      = (const float*)d_in[2];
  float* out = (float*)d_out;

  char* ws = (char*)d_ws;
  int*            idx  = (int*)ws;                       // 8 KB
  __hip_bfloat16* z1   = (__hip_bfloat16*)(ws + 8192);   // 512 KB
  __hip_bfloat16* w2T  = (__hip_bfloat16*)(ws + 532480); // 12.87 MB
  float*          pmax = (float*)(ws + 13398272);        // 3.22 MB
  float*          psum = (float*)(ws + 16617728);        // 3.22 MB
  float*          m2   = (float*)(ws + 19837184);        // 64 KB
  float*          s2   = (float*)(ws + 19902720);        // 64 KB
  float*          lse  = (float*)(ws + 19968256);        // 8 KB  (total ~19.98 MB)

  long n4 = ((long)NB * VOCAB) >> 2;
  k_find_idx<<<2048, 256, 0, stream>>>((const float4*)one_hot, idx, n4);
  k_transpose<<<(VOCAB + 63) / 64, 256, 0, stream>>>(w2, w2T);
  k_gather<<<NB * NE / 256, 256, 0, stream>>>(w1, idx, z1);
  k_gemm<true><<<NWG, 256, 0, stream>>>(z1, w2T, nullptr, pmax, psum, nullptr);
  k_lse_part<<<dim3(NB / 256, 8), 256, 0, stream>>>(pmax, psum, m2, s2);
  k_lse_final<<<NB / 256, 256, 0, stream>>>(m2, s2, lse);
  k_gemm<false><<<NWG, 256, 0, stream>>>(z1, w2T, lse, nullptr, nullptr, out);
}

// Round 3
// 369.634 us; speedup vs baseline: 1.8595x; 1.8595x over previous
//
#include <hip/hip_runtime.h>
#include <hip/hip_bf16.h>

#define VOCAB 50257
#define NB    2048
#define NE    128
#define NCH   393              // ceil(VOCAB/128)
#define NWG   (NCH * (NB/128)) // 6288 = 8 * 786

typedef __bf16 bf16x8 __attribute__((ext_vector_type(8)));
typedef float  f32x4  __attribute__((ext_vector_type(4)));

// ---------------- kernel 1: recover indices, one wave per row, early exit ----------------
__global__ __launch_bounds__(256) void k_find_idx(const float* __restrict__ oh, int* __restrict__ idx) {
  const int w    = (blockIdx.x * 256 + threadIdx.x) >> 6;   // row
  const int lane = threadIdx.x & 63;
  if (w >= NB) return;
  const float* row = oh + (long)w * VOCAB;
  const int a = (4 - (w & 3)) & 3;            // first 16B-aligned element of this row
  const f32x4* rp = reinterpret_cast<const f32x4*>(row + a);

  bool done = false;
  // vector region: [a, a+49152), 48 iters x 1024 elements/wave
  for (int i = 0; i < 48; ++i) {
    f32x4 v[4];
#pragma unroll
    for (int j = 0; j < 4; ++j) v[j] = rp[i * 256 + j * 64 + lane];
    bool f = false;
#pragma unroll
    for (int j = 0; j < 4; ++j)
      f |= (v[j][0] != 0.f) | (v[j][1] != 0.f) | (v[j][2] != 0.f) | (v[j][3] != 0.f);
    if (__any(f)) {
#pragma unroll
      for (int j = 0; j < 4; ++j)
#pragma unroll
        for (int k = 0; k < 4; ++k)
          if (v[j][k] != 0.f) idx[w] = a + (i * 256 + j * 64 + lane) * 4 + k;
      done = true;
      break;
    }
  }
  if (!done) {
    // head [0,a) and tail [a+49152, VOCAB)
    if (lane < a && row[lane] != 0.f) idx[w] = lane;
    for (int e = a + 49152 + lane; e < VOCAB; e += 64)
      if (row[e] != 0.f) idx[w] = e;
  }
}

// ---------------- kernel 2: w2 [128][V] f32 -> w2T [V][128] bf16 ----------------
__global__ void k_transpose(const float* __restrict__ w2, __hip_bfloat16* __restrict__ w2T) {
  __shared__ __hip_bfloat16 tile[64][130];
  const int v0 = blockIdx.x * 64;
  const int tv = threadIdx.x & 63;
  const int te = threadIdx.x >> 6;   // 0..3
  const int v  = v0 + tv;
#pragma unroll
  for (int e0 = 0; e0 < NE; e0 += 4) {
    int e = e0 + te;
    float val = (v < VOCAB) ? w2[(long)e * VOCAB + v] : 0.f;
    tile[tv][e] = __float2bfloat16(val);
  }
  __syncthreads();
#pragma unroll
  for (int it = 0; it < 16; ++it) {
    int f  = it * 256 + threadIdx.x;
    int r  = f >> 6;
    int c2 = f & 63;
    int vv = v0 + r;
    if (vv < VOCAB) {
      ushort2 p;
      p.x = *reinterpret_cast<const unsigned short*>(&tile[r][2 * c2]);
      p.y = *reinterpret_cast<const unsigned short*>(&tile[r][2 * c2 + 1]);
      reinterpret_cast<ushort2*>(w2T + (long)vv * NE)[c2] = p;
    }
  }
}

// ---------------- kernel 3: z1[b] = bf16(w1[idx[b]]) ----------------
__global__ void k_gather(const float* __restrict__ w1, const int* __restrict__ idx,
                         __hip_bfloat16* __restrict__ z1) {
  int t = blockIdx.x * blockDim.x + threadIdx.x;   // NB*NE threads
  int b = t >> 7, e = t & 127;
  z1[t] = __float2bfloat16(w1[(long)idx[b] * NE + e]);
}

// ---------------- GEMM (operand-swapped): acc[vi][ri] = w2T-frag x z1-frag ----------------
// D layout: z-row = l15, vocab col = lhi*4 + reg (within 16-tile vi) ->
// lane holds 4 consecutive vocab cols of one row per acc reg.
template <bool LSE_PASS>
__global__ __launch_bounds__(256) void k_gemm(
    const __hip_bfloat16* __restrict__ z1,
    const __hip_bfloat16* __restrict__ w2T,
    const float* __restrict__ lse,
    float* __restrict__ pmax, float* __restrict__ psum,
    float* __restrict__ out) {
  // XCD-chunked swizzle: bid%8 = XCD; contiguous chunk-major slice per XCD.
  const int bid = blockIdx.x;
  const int g = (bid & 7) * (NWG / 8) + (bid >> 3);
  const int chunk = g >> 4;          // 0..392 vocab 128-col chunk
  const int rowg  = g & 15;          // 0..15  batch 128-row group
  const int lane = threadIdx.x & 63;
  const int wave = threadIdx.x >> 6;
  const int wm = wave >> 1, wn = wave & 1;
  const int l15 = lane & 15, lhi = lane >> 4;
  const int row0 = rowg * 128 + wm * 64;
  const int col0 = chunk * 128 + wn * 64;

  bf16x8 bz[4][4];
  {
    const __hip_bfloat16* zp = z1 + (row0 + l15) * NE + lhi * 8;
#pragma unroll
    for (int ri = 0; ri < 4; ++ri)
#pragma unroll
      for (int kb = 0; kb < 4; ++kb)
        bz[ri][kb] = *reinterpret_cast<const bf16x8*>(zp + ri * 16 * NE + kb * 32);
  }

  f32x4 acc[4][4];   // [vi][ri]
#pragma unroll
  for (int vi = 0; vi < 4; ++vi)
#pragma unroll
    for (int ri = 0; ri < 4; ++ri)
      acc[vi][ri] = (f32x4){0.f, 0.f, 0.f, 0.f};

#pragma unroll
  for (int vi = 0; vi < 4; ++vi) {
    int col  = col0 + vi * 16 + l15;
    int colc = col < VOCAB ? col : VOCAB - 1;   // clamped dup, masked in epilogue
    const __hip_bfloat16* wp = w2T + colc * NE + lhi * 8;
    bf16x8 aw[4];
#pragma unroll
    for (int kb = 0; kb < 4; ++kb)
      aw[kb] = *reinterpret_cast<const bf16x8*>(wp + kb * 32);
#pragma unroll
    for (int ri = 0; ri < 4; ++ri)
#pragma unroll
      for (int kb = 0; kb < 4; ++kb)
        acc[vi][ri] = __builtin_amdgcn_mfma_f32_16x16x32_bf16(aw[kb], bz[ri][kb], acc[vi][ri], 0, 0, 0);
  }

  if constexpr (LSE_PASS) {
    __shared__ float sm[2][128];
    __shared__ float ss[2][128];
#pragma unroll
    for (int ri = 0; ri < 4; ++ri) {
      float v[16];
      float m = -INFINITY;
#pragma unroll
      for (int vi = 0; vi < 4; ++vi)
#pragma unroll
        for (int r = 0; r < 4; ++r) {
          int col = col0 + vi * 16 + lhi * 4 + r;
          float x = (col < VOCAB) ? acc[vi][ri][r] : -INFINITY;
          v[vi * 4 + r] = x;
          m = fmaxf(m, x);
        }
      m = fmaxf(m, __shfl_xor(m, 16));
      m = fmaxf(m, __shfl_xor(m, 32));
      float s = 0.f;
#pragma unroll
      for (int t = 0; t < 16; ++t) s += __expf(v[t] - m);
      s += __shfl_xor(s, 16);
      s += __shfl_xor(s, 32);
      if (lhi == 0) {
        int lr = wm * 64 + ri * 16 + l15;
        sm[wn][lr] = m;
        ss[wn][lr] = s;
      }
    }
    __syncthreads();
    if (threadIdx.x < 128) {
      int r = threadIdx.x;
      float m0 = sm[0][r], m1 = sm[1][r];
      float s0 = ss[0][r], s1 = ss[1][r];
      float M = fmaxf(m0, m1);
      float S = s0 * __expf(m0 - M) + s1 * __expf(m1 - M);
      int o = chunk * NB + rowg * 128 + r;
      pmax[o] = M;
      psum[o] = S;
    }
  } else {
    // LDS-staged coalesced epilogue: two 64-row halves, 33.8KB LDS
    __shared__ float tile[64][132];
    float lsev[4];
#pragma unroll
    for (int ri = 0; ri < 4; ++ri) lsev[ri] = lse[row0 + ri * 16 + l15];

#pragma unroll
    for (int half = 0; half < 2; ++half) {
      if (wm == half) {
#pragma unroll
        for (int vi = 0; vi < 4; ++vi)
#pragma unroll
          for (int ri = 0; ri < 4; ++ri) {
            f32x4 v = acc[vi][ri] - lsev[ri];
            *reinterpret_cast<f32x4*>(&tile[ri * 16 + l15][wn * 64 + vi * 16 + lhi * 4]) = v;
          }
      }
      __syncthreads();
      // store 64 rows x 128 cols, contiguous 512B per row
      int r = threadIdx.x >> 5;          // 0..7
      int c = (threadIdx.x & 31) * 4;    // 0..124
#pragma unroll
      for (int it = 0; it < 8; ++it) {
        int rr = it * 8 + r;
        int grow = rowg * 128 + half * 64 + rr;
        int gcol = chunk * 128 + c;
        f32x4 v = *reinterpret_cast<const f32x4*>(&tile[rr][c]);
        if (gcol + 3 < VOCAB) {
          *reinterpret_cast<f32x4*>(out + (long)grow * VOCAB + gcol) = v;
        } else {
#pragma unroll
          for (int k = 0; k < 4; ++k)
            if (gcol + k < VOCAB) out[(long)grow * VOCAB + gcol + k] = v[k];
        }
      }
      __syncthreads();
    }
  }
}

// ---------------- two-stage chunk-partial merge -> lse[b] ----------------
__global__ void k_lse_part(const float* __restrict__ pmax, const float* __restrict__ psum,
                           float* __restrict__ m2, float* __restrict__ s2) {
  int b  = blockIdx.x * 256 + threadIdx.x;
  int cg = blockIdx.y;
  int c0 = cg * 50, c1 = (c0 + 50 < NCH) ? c0 + 50 : NCH;
  float M = -INFINITY;
  for (int c = c0; c < c1; ++c) M = fmaxf(M, pmax[c * NB + b]);
  float S = 0.f;
  for (int c = c0; c < c1; ++c) S += psum[c * NB + b] * __expf(pmax[c * NB + b] - M);
  m2[cg * NB + b] = M;
  s2[cg * NB + b] = S;
}

__global__ void k_lse_final(const float* __restrict__ m2, const float* __restrict__ s2,
                            float* __restrict__ lse) {
  int b = blockIdx.x * 256 + threadIdx.x;
  float M = -INFINITY;
#pragma unroll
  for (int g = 0; g < 8; ++g) M = fmaxf(M, m2[g * NB + b]);
  float S = 0.f;
#pragma unroll
  for (int g = 0; g < 8; ++g) S += s2[g * NB + b] * __expf(m2[g * NB + b] - M);
  lse[b] = M + __logf(S);
}

extern "C" void kernel_launch(void* const* d_in, const int* in_sizes, int n_in,
                              void* d_out, int out_size, void* d_ws, size_t ws_size,
                              hipStream_t stream) {
  const float* one_hot = (const float*)d_in[0];
  const float* w1      = (const float*)d_in[1];
  const float* w2      = (const float*)d_in[2];
  float* out = (float*)d_out;

  char* ws = (char*)d_ws;
  int*            idx  = (int*)ws;                       // 8 KB
  __hip_bfloat16* z1   = (__hip_bfloat16*)(ws + 8192);   // 512 KB
  __hip_bfloat16* w2T  = (__hip_bfloat16*)(ws + 532480); // 12.87 MB
  float*          pmax = (float*)(ws + 13398272);        // 3.22 MB
  float*          psum = (float*)(ws + 16617728);        // 3.22 MB
  float*          m2   = (float*)(ws + 19837184);        // 64 KB
  float*          s2   = (float*)(ws + 19902720);        // 64 KB
  float*          lse  = (float*)(ws + 19968256);        // 8 KB

  k_find_idx<<<NB / 4, 256, 0, stream>>>(one_hot, idx);
  k_transpose<<<(VOCAB + 63) / 64, 256, 0, stream>>>(w2, w2T);
  k_gather<<<NB * NE / 256, 256, 0, stream>>>(w1, idx, z1);
  k_gemm<true><<<NWG, 256, 0, stream>>>(z1, w2T, nullptr, pmax, psum, nullptr);
  k_lse_part<<<dim3(NB / 256, 8), 256, 0, stream>>>(pmax, psum, m2, s2);
  k_lse_final<<<NB / 256, 256, 0, stream>>>(m2, s2, lse);
  k_gemm<false><<<NWG, 256, 0, stream>>>(z1, w2T, lse, nullptr, nullptr, out);
}